// Round 1
// 213.524 us; speedup vs baseline: 1.0215x; 1.0215x over previous
//
#include <hip/hip_runtime.h>
#include <hip/hip_bf16.h>

#define DIM    768
#define HEADS  12
#define DHEAD  64
#define BATCH  4
#define SEQ    2048
#define NROW   (BATCH * SEQ)   // 8192
#define QKVN   (3 * DIM)       // 2304
#define FACTOR 0.125f          // 64^-0.5
#define QSCALE 0.18033688011112042f  // FACTOR * log2(e), folded into Wqt rows <768

typedef __attribute__((ext_vector_type(8))) short short8;   // 8 bf16 = 4 VGPR
typedef __attribute__((ext_vector_type(4))) float floatx4;  // 16x16 C/D

__device__ __forceinline__ floatx4 mfma16(short8 a, short8 b, floatx4 c) {
    return __builtin_amdgcn_mfma_f32_16x16x32_bf16(a, b, c, 0, 0, 0);
}

// async global->LDS, 16B per lane; lds base must be wave-uniform,
// deposits at base + lane*16 (lane-ordered source REQUIRED for coalescing)
__device__ __forceinline__ void glds16(const void* g, void* l) {
    __builtin_amdgcn_global_load_lds((const __attribute__((address_space(1))) void*)g,
                                     (__attribute__((address_space(3))) void*)l,
                                     16, 0, 0);
}

// branchless RNE fp32->bf16 (finite values only)
__device__ __forceinline__ short rne16(float f) {
    unsigned u = __builtin_bit_cast(unsigned, f);
    return (short)((u + 0x7fffu + ((u >> 16) & 1u)) >> 16);
}
__device__ __forceinline__ unsigned pack2(float lo, float hi) {
    unsigned ul = __builtin_bit_cast(unsigned, lo);
    unsigned uh = __builtin_bit_cast(unsigned, hi);
    ul = (ul + 0x7fffu + ((ul >> 16) & 1u)) >> 16;
    uh = (uh + 0x7fffu + ((uh >> 16) & 1u)) & 0xffff0000u;
    return ul | uh;
}
// HW packed RNE cvt (gfx950): lo -> bits[15:0], hi -> bits[31:16]
__device__ __forceinline__ unsigned cvtpk(float lo, float hi) {
    unsigned r;
    asm("v_cvt_pk_bf16_f32 %0, %1, %2" : "=v"(r) : "v"(lo), "v"(hi));
    return r;
}

// XOR-swizzled tile addressing: 64 bf16 per row, swizzle 16B chunks.
__device__ __forceinline__ int swz8(int row, int col) {
    return (row << 6) + ((((col >> 3) ^ row) & 7) << 3) + (col & 7);
}

// ---------------------------------------------------------------------------
// prep (fused): blocks [0,6144)   : x fp32 -> bf16
//               blocks [6144,7872): Wqkv transpose+permute (+QSCALE rows<768)
//               blocks [7872,8448): Wout transpose
// ---------------------------------------------------------------------------
__global__ __launch_bounds__(256) void prep(const float* __restrict__ x,
                                            short* __restrict__ xb,
                                            const float* __restrict__ Wqkv,
                                            short* __restrict__ Wqt,
                                            const float* __restrict__ Wout,
                                            short* __restrict__ Wot) {
    __shared__ short T[32][33];
    int blk = blockIdx.x;
    if (blk < 6144) {
        int g = blk * 256 + threadIdx.x;
        float4 v = ((const float4*)x)[g];
        uint2 o;
        o.x = pack2(v.x, v.y);
        o.y = pack2(v.z, v.w);
        ((uint2*)xb)[g] = o;
        return;
    }
    blk -= 6144;
    const float* W;
    short* Wt;
    int N, permute, bx, by;
    if (blk < 1728) { W = Wqkv; Wt = Wqt; N = QKVN; permute = 1; bx = blk % 72; by = blk / 72; }
    else { blk -= 1728; W = Wout; Wt = Wot; N = DIM; permute = 0; bx = blk % 24; by = blk / 24; }

    int n0 = bx * 32, k0 = by * 32;
    int c = threadIdx.x & 31, r0 = threadIdx.x >> 5;
    for (int r = r0; r < 32; r += 8)
        T[r][c] = rne16(W[(size_t)(k0 + r) * N + n0 + c]);
    __syncthreads();
    for (int r = r0; r < 32; r += 8) {
        int n = n0 + r;
        int np = n;
        float scale = 1.0f;
        if (permute) {
            int d = n / 36, rem = n - d * 36;
            int which = rem / 12, h = rem - which * 12;
            np = which * 768 + h * 64 + d;
            if (which == 0) scale = QSCALE;
        }
        float v = __bfloat162float(__hip_bfloat16_raw{(unsigned short)T[c][r]});
        Wt[(size_t)np * DIM + k0 + c] = (scale == 1.0f) ? T[c][r] : rne16(v * scale);
    }
}

// ---------------------------------------------------------------------------
// qkv = xb @ Wqkv (via permuted Wqt [2304][768]); glds-staged.
// Outputs Q,K,V^T as XOR-swizzled 64x64 tiles [bh][32 tiles][4096 shorts].
// Q/K waves run the MFMA with SWAPPED operands (C^T): lane holds 4
// consecutive d at fixed t -> packed uint2 stores (16/lane, not 64 scalar).
// V waves keep orientation (4 consecutive t at fixed d) -> LDS transpose.
// ---------------------------------------------------------------------------
__global__ __launch_bounds__(256) void gemm_qkv(const short* __restrict__ A,
                                                const short* __restrict__ Bt,
                                                short* __restrict__ Qo,
                                                short* __restrict__ Ko,
                                                short* __restrict__ Vto) {
    __shared__ short As[128 * 64];
    __shared__ short Bs[128 * 64];
    const int tid = threadIdx.x;
    const int lane = tid & 63, wave = tid >> 6;
    const int l15 = lane & 15, quad = lane >> 4;

    // XCD swizzle: 8 XCDs x 8 m x 18 n = 1152 blocks
    const int flat = blockIdx.x;
    const int xcd = flat & 7;
    const int local = flat >> 3;
    const int mloc = local & 7, nloc = local >> 3;
    const int m0 = (xcd * 8 + mloc) * 128;
    const int n0 = nloc * 128;

    const int wm = (wave >> 1) * 64, wn = (wave & 1) * 64;
    const int r8 = wave * 8 + (lane >> 3);
    const int c8 = lane & 7;
    const int sc = ((c8 ^ (r8 & 7)) << 3);   // swizzled source chunk (elems)

    const int sn = n0 + wn;                  // wave-uniform output chunk
    const int which = sn / 768;
    const bool swapAB = (which != 2);        // Q/K waves compute C^T

    floatx4 acc[4][4] = {};
    for (int k0 = 0; k0 < DIM; k0 += 64) {
#pragma unroll
        for (int i = 0; i < 4; ++i) {
            int row = i * 32 + r8;
            glds16(&A[(size_t)(m0 + row) * DIM + k0 + sc], &As[(size_t)(i * 32 + wave * 8) * 64]);
            glds16(&Bt[(size_t)(n0 + row) * DIM + k0 + sc], &Bs[(size_t)(i * 32 + wave * 8) * 64]);
        }
        __syncthreads();
#pragma unroll
        for (int ks = 0; ks < 2; ++ks) {
            short8 a[4], b[4];
#pragma unroll
            for (int mt = 0; mt < 4; ++mt)
                a[mt] = *(const short8*)&As[swz8(wm + mt * 16 + l15, ks * 32 + quad * 8)];
#pragma unroll
            for (int nt = 0; nt < 4; ++nt)
                b[nt] = *(const short8*)&Bs[swz8(wn + nt * 16 + l15, ks * 32 + quad * 8)];
            if (swapAB) {
#pragma unroll
                for (int mt = 0; mt < 4; ++mt)
#pragma unroll
                    for (int nt = 0; nt < 4; ++nt)
                        acc[mt][nt] = mfma16(b[nt], a[mt], acc[mt][nt]);
            } else {
#pragma unroll
                for (int mt = 0; mt < 4; ++mt)
#pragma unroll
                    for (int nt = 0; nt < 4; ++nt)
                        acc[mt][nt] = mfma16(a[mt], b[nt], acc[mt][nt]);
            }
        }
        __syncthreads();
    }

    // ---- epilogue ----
    const int h = (sn - which * 768) >> 6;
    const int bb = (m0 + wm) >> 11;
    const int tbase = (m0 + wm) & 2047;
    const size_t tilebase = ((size_t)(bb * HEADS + h) * 32 + (tbase >> 6)) * 4096;

    if (which != 2) {
        // swapped acc: lane covers t = mt*16+l15, d = nt*16+quad*4..+3
        short* dst = (which == 0) ? Qo : Ko;
#pragma unroll
        for (int mt = 0; mt < 4; ++mt)
#pragma unroll
            for (int nt = 0; nt < 4; ++nt) {
                int tl = mt * 16 + l15;
                int d0 = nt * 16 + quad * 4;
                uint2 pk;
                pk.x = pack2(acc[mt][nt][0], acc[mt][nt][1]);
                pk.y = pack2(acc[mt][nt][2], acc[mt][nt][3]);
                *(uint2*)&dst[tilebase + swz8(tl, d0)] = pk;
            }
    } else {
        // V: build the swizzled V^T 64x64 tile in LDS (vld IS the tile image)
        short* vld = ((wave < 2) ? As : Bs) + (wave & 1) * 4096;  // 64x64
#pragma unroll
        for (int mt = 0; mt < 4; ++mt)
#pragma unroll
            for (int nt = 0; nt < 4; ++nt) {
                int d = nt * 16 + l15;
                int tl = mt * 16 + quad * 4;
                int chunk = (tl >> 3) ^ (d & 7);
                int addr = (d << 6) + (chunk << 3) + (tl & 7);   // = swz8(d, tl)
                uint2 pk;
                pk.x = pack2(acc[mt][nt][0], acc[mt][nt][1]);
                pk.y = pack2(acc[mt][nt][2], acc[mt][nt][3]);
                *(uint2*)&vld[addr] = pk;
            }
    }
    __syncthreads();
    if (which == 2) {
        // linear dump of the swizzled tile -> perfectly coalesced dwordx4
        short* vld = ((wave < 2) ? As : Bs) + (wave & 1) * 4096;
#pragma unroll
        for (int i = 0; i < 8; ++i) {
            int c = (i * 64 + lane) * 8;
            *(uint4*)&Vto[tilebase + c] = *(const uint4*)&vld[c];
        }
    }
}

// ---------------------------------------------------------------------------
// MFMA flash attention, WAVE-INDEPENDENT restructure:
//   4 waves/block, each wave owns 32 q rows over the FULL 64-kv tile.
//   - P tile is PRIVATE per wave (LDS strip, wave-internal lgkm ordering,
//     no barrier between QK and PV).
//   - K/V double-buffered; prefetch issued right after the single
//     top-of-iter barrier -> vmcnt(0) drain lands after a full compute
//     phase (T3 minimum-2-phase).
//   - PV uses swapped operands: o = mfma(V^T-frag, P^T-frag) -> C col = q,
//     row = d; epilogue normalization is per-lane (inv at l15 = q), no
//     shfl-broadcast, no pair reduce, uint2 packed stores.
//   Barriers per kv-iter: 3 -> 1.
// ---------------------------------------------------------------------------
__global__ __launch_bounds__(256, 3) void attn_mfma(const short* __restrict__ Q,
                                                    const short* __restrict__ K,
                                                    const short* __restrict__ Vt,
                                                    short* __restrict__ O) {
    // [0,16384): K/V double buffer (2 x (K 4096 | V 4096))
    // [16384,24576): per-wave private P strips (4 x 2048 shorts = 32q x 64kv)
    __shared__ __align__(16) short smem[24576];   // 48 KB -> 3 blocks/CU
    const int tid = threadIdx.x;
    const int lane = tid & 63, wave = tid >> 6;
    const int l15 = lane & 15, quad = lane >> 4;
    const int flat = blockIdx.x;
    const int xcd = flat & 7, li = flat >> 3;      // li 0..95
    const int bh = xcd + (li % 6) * 8;             // bh % 8 == xcd (K/V L2-local)
    const int q0 = (li / 6) * 128;
    const size_t base = (size_t)bh * SEQ * DHEAD;  // shorts; = bh*32 tiles
    short* Pp = smem + 16384 + wave * 2048;
    const int lane8 = lane * 8;

    // ---- stage Q (2 swizzled tiles, 16 KB) into smem[0..8191] ----
    {
        size_t qtb = base + (size_t)(q0 >> 6) * 4096;
#pragma unroll
        for (int c = 0; c < 4; ++c) {
            int i = wave * 4 + c;
            glds16(&Q[qtb + (size_t)i * 512 + lane8], &smem[i * 512]);
        }
    }
    __syncthreads();
    short8 qf[2][2];   // wave's 32 q rows: [mt][ks]
#pragma unroll
    for (int mt = 0; mt < 2; ++mt)
#pragma unroll
        for (int ks = 0; ks < 2; ++ks)
            qf[mt][ks] = *(const short8*)&smem[(wave >> 1) * 4096 +
                                               swz8((wave & 1) * 32 + mt * 16 + l15,
                                                    ks * 32 + quad * 8)];
    __syncthreads();   // Q in regs; smem free for K/V dbuf

    floatx4 o[4][2] = {};        // [dt][mt]: C col=q(l15), row=d(quad*4+r)
    float lsum[2] = {0.f, 0.f};

    // prologue: stage kv-tile 0 into buf0
    {
#pragma unroll
        for (int c = 0; c < 2; ++c) {
            int i = wave * 2 + c;
            glds16(&K[base + i * 512 + lane8], &smem[i * 512]);
            glds16(&Vt[base + i * 512 + lane8], &smem[4096 + i * 512]);
        }
    }

    for (int t = 0; t < 32; ++t) {
        __syncthreads();          // implicit vmcnt(0): tile t resident; buf[t+1&1] free
        short* Ks = smem + (t & 1) * 8192;
        short* Vs = Ks + 4096;
        if (t < 31) {             // prefetch t+1; drains only at NEXT barrier
            size_t ktb = base + (size_t)(t + 1) * 4096;
            short* nb = smem + ((t + 1) & 1) * 8192;
#pragma unroll
            for (int c = 0; c < 2; ++c) {
                int i = wave * 2 + c;
                glds16(&K[ktb + i * 512 + lane8], &nb[i * 512]);
                glds16(&Vt[ktb + i * 512 + lane8], &nb[4096 + i * 512]);
            }
        }

        // ---- S^T = K . Q^T : sa[kt][mt], kv = kt*16+quad*4+r, q = mt*16+l15
        floatx4 sa[4][2] = {};
        __builtin_amdgcn_s_setprio(1);
#pragma unroll
        for (int ks = 0; ks < 2; ++ks)
#pragma unroll
            for (int kt = 0; kt < 4; ++kt) {
                short8 kf = *(const short8*)&Ks[swz8(kt * 16 + l15, ks * 32 + quad * 8)];
                sa[kt][0] = mfma16(kf, qf[0][ks], sa[kt][0]);
                sa[kt][1] = mfma16(kf, qf[1][ks], sa[kt][1]);
            }
        __builtin_amdgcn_s_setprio(0);

        // ---- p = exp2(s) -> private P tile (wave-internal, no barrier) ----
#pragma unroll
        for (int kt = 0; kt < 4; ++kt)
#pragma unroll
            for (int mt = 0; mt < 2; ++mt) {
                float p0 = __builtin_amdgcn_exp2f(sa[kt][mt][0]);
                float p1 = __builtin_amdgcn_exp2f(sa[kt][mt][1]);
                float p2 = __builtin_amdgcn_exp2f(sa[kt][mt][2]);
                float p3 = __builtin_amdgcn_exp2f(sa[kt][mt][3]);
                lsum[mt] += (p0 + p1) + (p2 + p3);
                uint2 pk;
                pk.x = cvtpk(p0, p1);
                pk.y = cvtpk(p2, p3);
                *(uint2*)&Pp[swz8(mt * 16 + l15, kt * 16 + quad * 4)] = pk;
            }

        // ---- O^T += V^T . P^T (swapped: A=V^T rows d, B=P^T cols q) ----
#pragma unroll
        for (int ks = 0; ks < 2; ++ks) {
            short8 pf0 = *(const short8*)&Pp[swz8(l15, ks * 32 + quad * 8)];
            short8 pf1 = *(const short8*)&Pp[swz8(16 + l15, ks * 32 + quad * 8)];
            __builtin_amdgcn_s_setprio(1);
#pragma unroll
            for (int dt = 0; dt < 4; ++dt) {
                short8 vf = *(const short8*)&Vs[swz8(dt * 16 + l15, ks * 32 + quad * 8)];
                o[dt][0] = mfma16(vf, pf0, o[dt][0]);
                o[dt][1] = mfma16(vf, pf1, o[dt][1]);
            }
            __builtin_amdgcn_s_setprio(0);
        }
    }

    // ---- epilogue: per-lane normalization (q = l15), packed stores ----
    float s0 = lsum[0], s1 = lsum[1];
    s0 += __shfl_xor(s0, 16); s0 += __shfl_xor(s0, 32);
    s1 += __shfl_xor(s1, 16); s1 += __shfl_xor(s1, 32);
    float inv0 = 1.f / s0;
    float inv1 = 1.f / s1;

    const int b = bh / HEADS, h = bh - b * HEADS;
#pragma unroll
    for (int mt = 0; mt < 2; ++mt) {
        int tq = q0 + wave * 32 + mt * 16 + l15;
        float iv = mt ? inv1 : inv0;
        size_t rowo = ((size_t)(b * SEQ + tq)) * DIM + h * DHEAD + quad * 4;
#pragma unroll
        for (int dt = 0; dt < 4; ++dt) {
            uint2 pk;
            pk.x = cvtpk(o[dt][mt][0] * iv, o[dt][mt][1] * iv);
            pk.y = cvtpk(o[dt][mt][2] * iv, o[dt][mt][3] * iv);
            *(uint2*)&O[rowo + dt * 16] = pk;
        }
    }
}

// ---------------------------------------------------------------------------
// out = attnB @ Wout (via Wot [768][768]), fp32 output; glds-staged.
// All waves SWAP operands (C^T): lane holds 4 consecutive n at fixed m ->
// one dwordx4 store per acc (16/lane, not 64 scalar dwords).
// ---------------------------------------------------------------------------
__global__ __launch_bounds__(256) void gemm_out(const short* __restrict__ A,
                                                const short* __restrict__ Bt,
                                                float* __restrict__ out) {
    __shared__ short As[128 * 64];
    __shared__ short Bs[128 * 64];
    const int tid = threadIdx.x;
    const int lane = tid & 63, wave = tid >> 6;
    const int l15 = lane & 15, quad = lane >> 4;
    const int m0 = blockIdx.y * 128, n0 = blockIdx.x * 128;
    const int wm = (wave >> 1) * 64, wn = (wave & 1) * 64;
    const int r8 = wave * 8 + (lane >> 3);
    const int sc = (((lane & 7) ^ (r8 & 7)) << 3);

    floatx4 acc[4][4] = {};
    for (int k0 = 0; k0 < DIM; k0 += 64) {
#pragma unroll
        for (int i = 0; i < 4; ++i) {
            int row = i * 32 + r8;
            glds16(&A[(size_t)(m0 + row) * DIM + k0 + sc], &As[(size_t)(i * 32 + wave * 8) * 64]);
            glds16(&Bt[(size_t)(n0 + row) * DIM + k0 + sc], &Bs[(size_t)(i * 32 + wave * 8) * 64]);
        }
        __syncthreads();
#pragma unroll
        for (int ks = 0; ks < 2; ++ks) {
            short8 a[4], b[4];
#pragma unroll
            for (int mt = 0; mt < 4; ++mt)
                a[mt] = *(const short8*)&As[swz8(wm + mt * 16 + l15, ks * 32 + quad * 8)];
#pragma unroll
            for (int nt = 0; nt < 4; ++nt)
                b[nt] = *(const short8*)&Bs[swz8(wn + nt * 16 + l15, ks * 32 + quad * 8)];
#pragma unroll
            for (int mt = 0; mt < 4; ++mt)
#pragma unroll
                for (int nt = 0; nt < 4; ++nt)
                    acc[mt][nt] = mfma16(b[nt], a[mt], acc[mt][nt]);  // C^T
        }
        __syncthreads();
    }

    // swapped: m = wm+mt*16+l15, n = wn+nt*16+quad*4..+3 -> dwordx4 stores
#pragma unroll
    for (int mt = 0; mt < 4; ++mt)
#pragma unroll
        for (int nt = 0; nt < 4; ++nt) {
            int m = m0 + wm + mt * 16 + l15;
            int n = n0 + wn + nt * 16 + quad * 4;
            *(floatx4*)&out[(size_t)m * DIM + n] = acc[mt][nt];
        }
}

// ---------------------------------------------------------------------------
extern "C" void kernel_launch(void* const* d_in, const int* in_sizes, int n_in,
                              void* d_out, int out_size, void* d_ws, size_t ws_size,
                              hipStream_t stream) {
    const float* x    = (const float*)d_in[0];  // [4,2048,768] fp32
    const float* Wqkv = (const float*)d_in[1];  // [768,2304]  fp32
    const float* Wout = (const float*)d_in[2];  // [768,768]   fp32
    float* out = (float*)d_out;                 // [4,2048,768] fp32

    const size_t NE = (size_t)NROW * DIM;       // 6291456
    short* xb  = (short*)d_ws;                  // x bf16; later reused as attnB
    short* Wqt = xb + NE;                       // [2304][768] (col-permuted, Q-rows pre-scaled)
    short* Wot = Wqt + (size_t)QKVN * DIM;      // [768][768]
    short* Qw  = Wot + (size_t)DIM * DIM;       // swizzled tiles
    short* Kw  = Qw + NE;                       // swizzled tiles
    short* Vtw = Kw + NE;                       // swizzled V^T tiles

    prep<<<6144 + 1728 + 576, 256, 0, stream>>>(x, xb, Wqkv, Wqt, Wout, Wot);
    gemm_qkv<<<8 * 8 * 18, 256, 0, stream>>>(xb, Wqt, Qw, Kw, Vtw);
    // xb (x in bf16) is dead after gemm_qkv -> reuse as attention output buffer
    attn_mfma<<<768, 256, 0, stream>>>(Qw, Kw, Vtw, xb);
    gemm_out<<<dim3(DIM / 128, NROW / 128), 256, 0, stream>>>(xb, Wot, out);
}

// Round 2
// 210.116 us; speedup vs baseline: 1.0380x; 1.0162x over previous
//
#include <hip/hip_runtime.h>
#include <hip/hip_bf16.h>

#define DIM    768
#define HEADS  12
#define DHEAD  64
#define BATCH  4
#define SEQ    2048
#define NROW   (BATCH * SEQ)   // 8192
#define QKVN   (3 * DIM)       // 2304
#define FACTOR 0.125f          // 64^-0.5
#define QSCALE 0.18033688011112042f  // FACTOR * log2(e), folded into Wqt rows <768

typedef __attribute__((ext_vector_type(8))) short short8;   // 8 bf16 = 4 VGPR
typedef __attribute__((ext_vector_type(4))) float floatx4;  // 16x16 C/D

__device__ __forceinline__ floatx4 mfma16(short8 a, short8 b, floatx4 c) {
    return __builtin_amdgcn_mfma_f32_16x16x32_bf16(a, b, c, 0, 0, 0);
}

// async global->LDS, 16B per lane; lds base must be wave-uniform,
// deposits at base + lane*16 (lane-ordered source REQUIRED for coalescing)
__device__ __forceinline__ void glds16(const void* g, void* l) {
    __builtin_amdgcn_global_load_lds((const __attribute__((address_space(1))) void*)g,
                                     (__attribute__((address_space(3))) void*)l,
                                     16, 0, 0);
}

// branchless RNE fp32->bf16 (finite values only)
__device__ __forceinline__ short rne16(float f) {
    unsigned u = __builtin_bit_cast(unsigned, f);
    return (short)((u + 0x7fffu + ((u >> 16) & 1u)) >> 16);
}
__device__ __forceinline__ unsigned pack2(float lo, float hi) {
    unsigned ul = __builtin_bit_cast(unsigned, lo);
    unsigned uh = __builtin_bit_cast(unsigned, hi);
    ul = (ul + 0x7fffu + ((ul >> 16) & 1u)) >> 16;
    uh = (uh + 0x7fffu + ((uh >> 16) & 1u)) & 0xffff0000u;
    return ul | uh;
}
// HW packed RNE cvt (gfx950): lo -> bits[15:0], hi -> bits[31:16]
__device__ __forceinline__ unsigned cvtpk(float lo, float hi) {
    unsigned r;
    asm("v_cvt_pk_bf16_f32 %0, %1, %2" : "=v"(r) : "v"(lo), "v"(hi));
    return r;
}

// XOR-swizzled tile addressing: 64 bf16 per row, swizzle 16B chunks.
__device__ __forceinline__ int swz8(int row, int col) {
    return (row << 6) + ((((col >> 3) ^ row) & 7) << 3) + (col & 7);
}

// ---------------------------------------------------------------------------
// prep (fused): blocks [0,6144)   : x fp32 -> bf16
//               blocks [6144,7872): Wqkv transpose+permute (+QSCALE rows<768)
//               blocks [7872,8448): Wout transpose
// ---------------------------------------------------------------------------
__global__ __launch_bounds__(256) void prep(const float* __restrict__ x,
                                            short* __restrict__ xb,
                                            const float* __restrict__ Wqkv,
                                            short* __restrict__ Wqt,
                                            const float* __restrict__ Wout,
                                            short* __restrict__ Wot) {
    __shared__ short T[32][33];
    int blk = blockIdx.x;
    if (blk < 6144) {
        int g = blk * 256 + threadIdx.x;
        float4 v = ((const float4*)x)[g];
        uint2 o;
        o.x = pack2(v.x, v.y);
        o.y = pack2(v.z, v.w);
        ((uint2*)xb)[g] = o;
        return;
    }
    blk -= 6144;
    const float* W;
    short* Wt;
    int N, permute, bx, by;
    if (blk < 1728) { W = Wqkv; Wt = Wqt; N = QKVN; permute = 1; bx = blk % 72; by = blk / 72; }
    else { blk -= 1728; W = Wout; Wt = Wot; N = DIM; permute = 0; bx = blk % 24; by = blk / 24; }

    int n0 = bx * 32, k0 = by * 32;
    int c = threadIdx.x & 31, r0 = threadIdx.x >> 5;
    for (int r = r0; r < 32; r += 8)
        T[r][c] = rne16(W[(size_t)(k0 + r) * N + n0 + c]);
    __syncthreads();
    for (int r = r0; r < 32; r += 8) {
        int n = n0 + r;
        int np = n;
        float scale = 1.0f;
        if (permute) {
            int d = n / 36, rem = n - d * 36;
            int which = rem / 12, h = rem - which * 12;
            np = which * 768 + h * 64 + d;
            if (which == 0) scale = QSCALE;
        }
        float v = __bfloat162float(__hip_bfloat16_raw{(unsigned short)T[c][r]});
        Wt[(size_t)np * DIM + k0 + c] = (scale == 1.0f) ? T[c][r] : rne16(v * scale);
    }
}

// ---------------------------------------------------------------------------
// qkv = xb @ Wqkv (via permuted Wqt [2304][768]); glds-staged.
// Outputs Q,K,V^T as XOR-swizzled 64x64 tiles [bh][32 tiles][4096 shorts].
// Q/K waves run the MFMA with SWAPPED operands (C^T): lane holds 4
// consecutive d at fixed t -> packed uint2 stores (16/lane, not 64 scalar).
// V waves keep orientation (4 consecutive t at fixed d) -> LDS transpose.
// ---------------------------------------------------------------------------
__global__ __launch_bounds__(256) void gemm_qkv(const short* __restrict__ A,
                                                const short* __restrict__ Bt,
                                                short* __restrict__ Qo,
                                                short* __restrict__ Ko,
                                                short* __restrict__ Vto) {
    __shared__ short As[128 * 64];
    __shared__ short Bs[128 * 64];
    const int tid = threadIdx.x;
    const int lane = tid & 63, wave = tid >> 6;
    const int l15 = lane & 15, quad = lane >> 4;

    // XCD swizzle: 8 XCDs x 8 m x 18 n = 1152 blocks
    const int flat = blockIdx.x;
    const int xcd = flat & 7;
    const int local = flat >> 3;
    const int mloc = local & 7, nloc = local >> 3;
    const int m0 = (xcd * 8 + mloc) * 128;
    const int n0 = nloc * 128;

    const int wm = (wave >> 1) * 64, wn = (wave & 1) * 64;
    const int r8 = wave * 8 + (lane >> 3);
    const int c8 = lane & 7;
    const int sc = ((c8 ^ (r8 & 7)) << 3);   // swizzled source chunk (elems)

    const int sn = n0 + wn;                  // wave-uniform output chunk
    const int which = sn / 768;
    const bool swapAB = (which != 2);        // Q/K waves compute C^T

    floatx4 acc[4][4] = {};
    for (int k0 = 0; k0 < DIM; k0 += 64) {
#pragma unroll
        for (int i = 0; i < 4; ++i) {
            int row = i * 32 + r8;
            glds16(&A[(size_t)(m0 + row) * DIM + k0 + sc], &As[(size_t)(i * 32 + wave * 8) * 64]);
            glds16(&Bt[(size_t)(n0 + row) * DIM + k0 + sc], &Bs[(size_t)(i * 32 + wave * 8) * 64]);
        }
        __syncthreads();
#pragma unroll
        for (int ks = 0; ks < 2; ++ks) {
            short8 a[4], b[4];
#pragma unroll
            for (int mt = 0; mt < 4; ++mt)
                a[mt] = *(const short8*)&As[swz8(wm + mt * 16 + l15, ks * 32 + quad * 8)];
#pragma unroll
            for (int nt = 0; nt < 4; ++nt)
                b[nt] = *(const short8*)&Bs[swz8(wn + nt * 16 + l15, ks * 32 + quad * 8)];
            if (swapAB) {
#pragma unroll
                for (int mt = 0; mt < 4; ++mt)
#pragma unroll
                    for (int nt = 0; nt < 4; ++nt)
                        acc[mt][nt] = mfma16(b[nt], a[mt], acc[mt][nt]);
            } else {
#pragma unroll
                for (int mt = 0; mt < 4; ++mt)
#pragma unroll
                    for (int nt = 0; nt < 4; ++nt)
                        acc[mt][nt] = mfma16(a[mt], b[nt], acc[mt][nt]);
            }
        }
        __syncthreads();
    }

    // ---- epilogue ----
    const int h = (sn - which * 768) >> 6;
    const int bb = (m0 + wm) >> 11;
    const int tbase = (m0 + wm) & 2047;
    const size_t tilebase = ((size_t)(bb * HEADS + h) * 32 + (tbase >> 6)) * 4096;

    if (which != 2) {
        // swapped acc: lane covers t = mt*16+l15, d = nt*16+quad*4..+3
        short* dst = (which == 0) ? Qo : Ko;
#pragma unroll
        for (int mt = 0; mt < 4; ++mt)
#pragma unroll
            for (int nt = 0; nt < 4; ++nt) {
                int tl = mt * 16 + l15;
                int d0 = nt * 16 + quad * 4;
                uint2 pk;
                pk.x = pack2(acc[mt][nt][0], acc[mt][nt][1]);
                pk.y = pack2(acc[mt][nt][2], acc[mt][nt][3]);
                *(uint2*)&dst[tilebase + swz8(tl, d0)] = pk;
            }
    } else {
        // V: build the swizzled V^T 64x64 tile in LDS (vld IS the tile image)
        short* vld = ((wave < 2) ? As : Bs) + (wave & 1) * 4096;  // 64x64
#pragma unroll
        for (int mt = 0; mt < 4; ++mt)
#pragma unroll
            for (int nt = 0; nt < 4; ++nt) {
                int d = nt * 16 + l15;
                int tl = mt * 16 + quad * 4;
                int chunk = (tl >> 3) ^ (d & 7);
                int addr = (d << 6) + (chunk << 3) + (tl & 7);   // = swz8(d, tl)
                uint2 pk;
                pk.x = pack2(acc[mt][nt][0], acc[mt][nt][1]);
                pk.y = pack2(acc[mt][nt][2], acc[mt][nt][3]);
                *(uint2*)&vld[addr] = pk;
            }
    }
    __syncthreads();
    if (which == 2) {
        // linear dump of the swizzled tile -> perfectly coalesced dwordx4
        short* vld = ((wave < 2) ? As : Bs) + (wave & 1) * 4096;
#pragma unroll
        for (int i = 0; i < 8; ++i) {
            int c = (i * 64 + lane) * 8;
            *(uint4*)&Vto[tilebase + c] = *(const uint4*)&vld[c];
        }
    }
}

// ---------------------------------------------------------------------------
// MFMA flash attention, 8 waves x 16 q-rows (TLP restore + R1 structure):
//   - each wave owns 16 q rows over the FULL 64-kv tile; P strictly private
//     (2 KB LDS strip/wave, wave-internal lgkm ordering, no QK->PV barrier)
//   - K/V double-buffered, prefetch issued right after the single
//     top-of-iter barrier (T3 minimum-2-phase)
//   - 512 thr -> 24 waves/CU at 3 blocks/CU (vs 12 in R1): 2x TLP to hide
//     the QK->exp2->P->PV chain
//   - per-lane epilogue normalization (inv at l15 = q), packed stores
// ---------------------------------------------------------------------------
__global__ __launch_bounds__(512, 6) void attn_mfma(const short* __restrict__ Q,
                                                    const short* __restrict__ K,
                                                    const short* __restrict__ Vt,
                                                    short* __restrict__ O) {
    // [0,16384): K/V double buffer (2 x (K 4096 | V 4096) shorts)
    // [16384,24576): per-wave private P strips (8 x 1024 shorts = 16q x 64kv)
    __shared__ __align__(16) short smem[24576];   // 48 KB -> 3 blocks/CU
    const int tid = threadIdx.x;
    const int lane = tid & 63, wave = tid >> 6;
    const int l15 = lane & 15, quad = lane >> 4;
    const int flat = blockIdx.x;
    const int xcd = flat & 7, li = flat >> 3;      // li 0..95
    const int bh = xcd + (li % 6) * 8;             // bh % 8 == xcd (K/V L2-local)
    const int q0 = (li / 6) * 128;
    const size_t base = (size_t)bh * SEQ * DHEAD;  // shorts; = bh*32 tiles
    short* Pp = smem + 16384 + wave * 1024;        // private 16x64 strip
    const int lane8 = lane * 8;

    // ---- stage Q (2 swizzled tiles, 16 KB) into smem[0..16383] ----
    {
        size_t qtb = base + (size_t)(q0 >> 6) * 4096;
#pragma unroll
        for (int c = 0; c < 2; ++c) {
            int i = wave * 2 + c;
            glds16(&Q[qtb + (size_t)i * 512 + lane8], &smem[i * 512]);
        }
    }
    __syncthreads();
    short8 qf[2];   // wave's 16 q rows: [ks]
#pragma unroll
    for (int ks = 0; ks < 2; ++ks)
        qf[ks] = *(const short8*)&smem[(wave >> 2) * 4096 +
                                       swz8((wave & 3) * 16 + l15,
                                            ks * 32 + quad * 8)];
    __syncthreads();   // Q in regs; smem free for K/V dbuf

    floatx4 o[4] = {};           // [dt]: C col=q(l15), row=d(quad*4+r)
    float lsum = 0.f;

    // prologue: stage kv-tile 0 into buf0 (1 K chunk + 1 V chunk per wave)
    glds16(&K[base + wave * 512 + lane8], &smem[wave * 512]);
    glds16(&Vt[base + wave * 512 + lane8], &smem[4096 + wave * 512]);

    for (int t = 0; t < 32; ++t) {
        __syncthreads();          // implicit vmcnt(0): tile t resident; other buf free
        short* Ks = smem + (t & 1) * 8192;
        short* Vs = Ks + 4096;
        if (t < 31) {             // prefetch t+1; drains only at NEXT barrier
            size_t ktb = base + (size_t)(t + 1) * 4096;
            short* nb = smem + ((t + 1) & 1) * 8192;
            glds16(&K[ktb + wave * 512 + lane8], &nb[wave * 512]);
            glds16(&Vt[ktb + wave * 512 + lane8], &nb[4096 + wave * 512]);
        }

        // ---- S^T = K . Q^T : sa[kt], kv = kt*16+quad*4+r, q = l15 ----
        floatx4 sa[4] = {};
        __builtin_amdgcn_s_setprio(1);
#pragma unroll
        for (int ks = 0; ks < 2; ++ks)
#pragma unroll
            for (int kt = 0; kt < 4; ++kt) {
                short8 kf = *(const short8*)&Ks[swz8(kt * 16 + l15, ks * 32 + quad * 8)];
                sa[kt] = mfma16(kf, qf[ks], sa[kt]);
            }
        __builtin_amdgcn_s_setprio(0);

        // ---- p = exp2(s) -> private P strip (wave-internal, no barrier) ----
#pragma unroll
        for (int kt = 0; kt < 4; ++kt) {
            float p0 = __builtin_amdgcn_exp2f(sa[kt][0]);
            float p1 = __builtin_amdgcn_exp2f(sa[kt][1]);
            float p2 = __builtin_amdgcn_exp2f(sa[kt][2]);
            float p3 = __builtin_amdgcn_exp2f(sa[kt][3]);
            lsum += (p0 + p1) + (p2 + p3);
            uint2 pk;
            pk.x = cvtpk(p0, p1);
            pk.y = cvtpk(p2, p3);
            *(uint2*)&Pp[swz8(l15, kt * 16 + quad * 4)] = pk;
        }

        // ---- O^T += V^T . P^T (A=V^T rows d, B=P^T cols q) ----
#pragma unroll
        for (int ks = 0; ks < 2; ++ks) {
            short8 pf = *(const short8*)&Pp[swz8(l15, ks * 32 + quad * 8)];
            __builtin_amdgcn_s_setprio(1);
#pragma unroll
            for (int dt = 0; dt < 4; ++dt) {
                short8 vf = *(const short8*)&Vs[swz8(dt * 16 + l15, ks * 32 + quad * 8)];
                o[dt] = mfma16(vf, pf, o[dt]);
            }
            __builtin_amdgcn_s_setprio(0);
        }
    }

    // ---- epilogue: per-lane normalization (q = l15), packed stores ----
    float s = lsum;
    s += __shfl_xor(s, 16);
    s += __shfl_xor(s, 32);
    float inv = 1.f / s;

    const int b = bh / HEADS, h = bh - b * HEADS;
    const int tq = q0 + wave * 16 + l15;
    size_t rowo = ((size_t)(b * SEQ + tq)) * DIM + h * DHEAD + quad * 4;
#pragma unroll
    for (int dt = 0; dt < 4; ++dt) {
        uint2 pk;
        pk.x = cvtpk(o[dt][0] * inv, o[dt][1] * inv);
        pk.y = cvtpk(o[dt][2] * inv, o[dt][3] * inv);
        *(uint2*)&O[rowo + dt * 16] = pk;
    }
}

// ---------------------------------------------------------------------------
// out = attnB @ Wout (via Wot [768][768]), fp32 output; glds-staged.
// All waves SWAP operands (C^T): lane holds 4 consecutive n at fixed m ->
// one dwordx4 store per acc (16/lane, not 64 scalar dwords).
// ---------------------------------------------------------------------------
__global__ __launch_bounds__(256) void gemm_out(const short* __restrict__ A,
                                                const short* __restrict__ Bt,
                                                float* __restrict__ out) {
    __shared__ short As[128 * 64];
    __shared__ short Bs[128 * 64];
    const int tid = threadIdx.x;
    const int lane = tid & 63, wave = tid >> 6;
    const int l15 = lane & 15, quad = lane >> 4;
    const int m0 = blockIdx.y * 128, n0 = blockIdx.x * 128;
    const int wm = (wave >> 1) * 64, wn = (wave & 1) * 64;
    const int r8 = wave * 8 + (lane >> 3);
    const int sc = (((lane & 7) ^ (r8 & 7)) << 3);

    floatx4 acc[4][4] = {};
    for (int k0 = 0; k0 < DIM; k0 += 64) {
#pragma unroll
        for (int i = 0; i < 4; ++i) {
            int row = i * 32 + r8;
            glds16(&A[(size_t)(m0 + row) * DIM + k0 + sc], &As[(size_t)(i * 32 + wave * 8) * 64]);
            glds16(&Bt[(size_t)(n0 + row) * DIM + k0 + sc], &Bs[(size_t)(i * 32 + wave * 8) * 64]);
        }
        __syncthreads();
#pragma unroll
        for (int ks = 0; ks < 2; ++ks) {
            short8 a[4], b[4];
#pragma unroll
            for (int mt = 0; mt < 4; ++mt)
                a[mt] = *(const short8*)&As[swz8(wm + mt * 16 + l15, ks * 32 + quad * 8)];
#pragma unroll
            for (int nt = 0; nt < 4; ++nt)
                b[nt] = *(const short8*)&Bs[swz8(wn + nt * 16 + l15, ks * 32 + quad * 8)];
#pragma unroll
            for (int mt = 0; mt < 4; ++mt)
#pragma unroll
                for (int nt = 0; nt < 4; ++nt)
                    acc[mt][nt] = mfma16(b[nt], a[mt], acc[mt][nt]);  // C^T
        }
        __syncthreads();
    }

    // swapped: m = wm+mt*16+l15, n = wn+nt*16+quad*4..+3 -> dwordx4 stores
#pragma unroll
    for (int mt = 0; mt < 4; ++mt)
#pragma unroll
        for (int nt = 0; nt < 4; ++nt) {
            int m = m0 + wm + mt * 16 + l15;
            int n = n0 + wn + nt * 16 + quad * 4;
            *(floatx4*)&out[(size_t)m * DIM + n] = acc[mt][nt];
        }
}

// ---------------------------------------------------------------------------
extern "C" void kernel_launch(void* const* d_in, const int* in_sizes, int n_in,
                              void* d_out, int out_size, void* d_ws, size_t ws_size,
                              hipStream_t stream) {
    const float* x    = (const float*)d_in[0];  // [4,2048,768] fp32
    const float* Wqkv = (const float*)d_in[1];  // [768,2304]  fp32
    const float* Wout = (const float*)d_in[2];  // [768,768]   fp32
    float* out = (float*)d_out;                 // [4,2048,768] fp32

    const size_t NE = (size_t)NROW * DIM;       // 6291456
    short* xb  = (short*)d_ws;                  // x bf16; later reused as attnB
    short* Wqt = xb + NE;                       // [2304][768] (col-permuted, Q-rows pre-scaled)
    short* Wot = Wqt + (size_t)QKVN * DIM;      // [768][768]
    short* Qw  = Wot + (size_t)DIM * DIM;       // swizzled tiles
    short* Kw  = Qw + NE;                       // swizzled tiles
    short* Vtw = Kw + NE;                       // swizzled V^T tiles

    prep<<<6144 + 1728 + 576, 256, 0, stream>>>(x, xb, Wqkv, Wqt, Wout, Wot);
    gemm_qkv<<<8 * 8 * 18, 256, 0, stream>>>(xb, Wqt, Qw, Kw, Vtw);
    // xb (x in bf16) is dead after gemm_qkv -> reuse as attention output buffer
    attn_mfma<<<768, 512, 0, stream>>>(Qw, Kw, Vtw, xb);
    gemm_out<<<dim3(DIM / 128, NROW / 128), 256, 0, stream>>>(xb, Wot, out);
}